// Round 19
// baseline (125.233 us; speedup 1.0000x reference)
//
#include <hip/hip_runtime.h>
#include <hip/hip_bf16.h>

#define NN_ 1024

// ws offsets. ushort: U_*; float: F_*  (~10.3 MB of the 256 MiB ws)
#define U_WGF  0         // 131072: Wg fragment-major REMAPPED:
                         //   ((jt*8+kb)*4+q)*128 + jl*8 + r ; source col
                         //   jorig = (jt&3)*128 + (jt>>2)*16 + jl (quadrant-interleaved)
#define U_SHI  131072    // 524288: W_soc bf16 hi, fragment-major ((g*4+j)*4+q)*512 + e*8 + r
#define U_ACTH 655360    // 262144: act_hi[n][k] 1024x256 (0-63 emb, 64-127 pool, 128-255 h0)
#define U_P    917504    // 4194304: P[m][g*64+e] bf16
#define F_WOUT 2555904   // 16384 f32: WoutT[r][j] 128x128, j>=120 zero

typedef __attribute__((ext_vector_type(8))) short short8;
typedef __attribute__((ext_vector_type(4))) float floatx4;

__device__ __forceinline__ float b2f_(unsigned short u) {
    return __uint_as_float(((unsigned)u) << 16);           // bf16 -> f32, exact
}
__device__ __forceinline__ unsigned short f2bu(float f) {  // f32 -> bf16 bits (RNE)
    __hip_bfloat16 b = __float2bfloat16(f);
    return *(unsigned short*)&b;
}
__device__ __forceinline__ float ldin(const void* p, int i, int isbf) {
    return isbf ? b2f_(((const unsigned short*)p)[i]) : ((const float*)p)[i];
}
__device__ __forceinline__ int detect_bf16(const void* Wih, int tid) {
    unsigned wv = ((const unsigned*)Wih)[tid];
    unsigned e8 = (wv >> 7) & 0xFFu;
    return (__syncthreads_count((e8 >= 96u && e8 <= 134u) ? 1 : 0) > 128) ? 1 : 0;
}

// ---- K0: one-time conversions, 8 elements/thread (424 blocks) ----
__global__ __launch_bounds__(256) void prep_kernel(
        const void* __restrict__ xoff, const void* __restrict__ h0,
        const void* __restrict__ Wsoc, const void* __restrict__ Wemb,
        const void* __restrict__ bemb, const void* __restrict__ Wih,
        const void* __restrict__ Whh,  const void* __restrict__ Wout,
        float* __restrict__ ws) {
    const int tid = threadIdx.x;
    const int isbf = detect_bf16(Wih, tid);
    unsigned short* u = (unsigned short*)ws;
    const int t0 = (blockIdx.x * 256 + tid) * 8;   // regions all 8-aligned
    unsigned short hv[8];
    if (t0 < 131072) {                             // Wg fragment-major, quadrant-remapped
        int jl = (t0 >> 3) & 15, q = (t0 >> 7) & 3, kb = (t0 >> 9) & 7, jt = t0 >> 12;
        int j = (jt & 3) * 128 + (jt >> 2) * 16 + jl;   // quadrant-interleaved source
        int k0 = kb * 32 + q * 8;
#pragma unroll
        for (int r = 0; r < 8; r++) {
            int k = k0 + r;
            float v = (k < 128) ? ldin(Wih, j * 128 + k, isbf)
                                : ldin(Whh, j * 128 + (k - 128), isbf);
            hv[r] = f2bu(v);
        }
        *(short8*)(u + U_WGF + t0) = *(short8*)hv;
    } else if (t0 < 147456) {                      // WoutT f32 [r][j]
        int t2 = t0 - 131072; int r = t2 >> 7, j0 = t2 & 127;
#pragma unroll
        for (int i = 0; i < 8; i++) {
            int j = j0 + i;
            ws[F_WOUT + t2 + i] = (j < 120) ? ldin(Wout, j * 128 + r, isbf) : 0.0f;
        }
    } else if (t0 < 671744) {                      // W_soc hi, fragment-major
        int t2 = t0 - 147456;
        int e = (t2 >> 3) & 63, q = (t2 >> 9) & 3, j = (t2 >> 11) & 3, g = t2 >> 13;
        int src = e * 8192 + g * 128 + j * 32 + q * 8;
#pragma unroll
        for (int r = 0; r < 8; r++) hv[r] = f2bu(ldin(Wsoc, src + r, isbf));
        *(short8*)(u + U_SHI + t2) = *(short8*)hv;
    } else if (t0 < 802816) {                      // h0 -> act k=128..255
        int t2 = t0 - 671744; int n = t2 >> 7, k = t2 & 127;
#pragma unroll
        for (int i = 0; i < 8; i++) hv[i] = f2bu(ldin(h0, t2 + i, isbf));
        *(short8*)(u + U_ACTH + n * 256 + 128 + k) = *(short8*)hv;
    } else {                                       // emb -> act k=0..63
        int t2 = t0 - 802816; int n = t2 >> 6, e0 = t2 & 63;
        float x0 = ldin(xoff, 2 * n, isbf), x1 = ldin(xoff, 2 * n + 1, isbf);
#pragma unroll
        for (int i = 0; i < 8; i++) {
            int e = e0 + i;
            float v = fmaf(x0, ldin(Wemb, 2 * e, isbf),
                      fmaf(x1, ldin(Wemb, 2 * e + 1, isbf), ldin(bemb, e, isbf)));
            hv[i] = f2bu(fmaxf(v, 0.0f));
        }
        *(short8*)(u + U_ACTH + n * 256 + e0) = *(short8*)hv;
    }
}

// ---- K1: P = h0 @ W_socT, hi-only MFMA (8/wave). 2048 blocks, coalesced B ----
__global__ __launch_bounds__(256) void pgemm_kernel(float* __restrict__ ws) {
    const unsigned short* u = (const unsigned short*)ws;
    const short* Ah  = (const short*)(u + U_ACTH);
    const short* Shi = (const short*)(u + U_SHI);
    unsigned short* P16 = (unsigned short*)ws + U_P;
    const int tid = threadIdx.x, lane = tid & 63, wv = tid >> 6;
    const int B_ = blockIdx.y * 64 + blockIdx.x;   // 0..2047
    const int mtile = B_ & 63, rest = B_ >> 6;
    const int cg = rest >> 1, thalf = rest & 1;
    const int m = lane & 15, q = lane >> 4;
    const int g = cg * 4 + wv;                     // wave-uniform B row-group
    const int abase = (mtile * 16 + m) * 256 + 128 + q * 8;
    short8 ah[4];
#pragma unroll
    for (int j = 0; j < 4; j++) ah[j] = *(const short8*)(Ah + abase + 32 * j);
    const int rowl = mtile * 16 + q * 4;
#pragma unroll
    for (int tt = 0; tt < 2; tt++) {
        const int t = thalf * 2 + tt;
        const int e = t * 16 + m;
        floatx4 c = {0.0f, 0.0f, 0.0f, 0.0f};
#pragma unroll
        for (int j = 0; j < 4; j++) {
            short8 bh = *(const short8*)(Shi + ((g * 4 + j) * 4 + q) * 512 + e * 8);
            c = __builtin_amdgcn_mfma_f32_16x16x32_bf16(ah[j], bh, c, 0, 0, 0);
        }
        const int n0 = cg * 256 + wv * 64 + t * 16;
#pragma unroll
        for (int r = 0; r < 4; r++)                // D: col=lane&15, row=q*4+r
            P16[(rowl + r) * 4096 + n0 + m] = f2bu(c[r]);
    }
}

// ---- K2: pool gather, 1 agent/block (1024 blocks); writes act k=64..127 ----
__global__ __launch_bounds__(256) void pool_kernel(const void* __restrict__ xabs,
                                                   const void* __restrict__ b_soc,
                                                   const void* __restrict__ Wih_det,
                                                   float* __restrict__ ws) {
    __shared__ float xabs_s[2048];
    __shared__ int   off[NN_];
    __shared__ int   cnt_s;
    __shared__ float4 red4[16][16];
    const int tid = threadIdx.x;
    const int isbf = detect_bf16(Wih_det, tid);
    const int n = blockIdx.x;
    unsigned short* u = (unsigned short*)ws;

    for (int i = tid; i < 2048; i += 256) xabs_s[i] = ldin(xabs, i, isbf);
    if (tid == 0) cnt_s = 0;
    __syncthreads();
    {
        float xs = xabs_s[2 * n]     - 0.2f;       // x[n] - NS/2
        float ys = xabs_s[2 * n + 1] - 0.2f;
        for (int i = tid; i < NN_; i += 256) {
            float dx = xabs_s[2 * i]     - xs;
            float dy = xabs_s[2 * i + 1] - ys;
            int cx = (int)floorf(dx / 0.4f * 8.0f);
            int cy = (int)floorf(dy / 0.4f * 8.0f);
            bool valid = (dx >= 0.0f) && (dx < 0.4f) && (dy >= 0.0f) && (dy < 0.4f)
                      && (cx >= 0) && (cx < 8) && (cy >= 0) && (cy < 8) && (i != n);
            if (valid) {
                int idx = atomicAdd(&cnt_s, 1);
                off[idx] = i * 4096 + ((cy * 8 + cx) << 6);
            }
        }
    }
    __syncthreads();
    {   // branch-free gathers: 16 streams x 16 e4-lanes
        const unsigned short* P16 = (const unsigned short*)ws + U_P;
        const int strm = tid >> 4, e4 = tid & 15;
        const int cc = cnt_s;
        float ax = 0.0f, ay = 0.0f, az = 0.0f, aw = 0.0f;
        for (int j = strm; j < cc; j += 16) {
            int o = off[j];
            ushort4 uu = *(const ushort4*)(P16 + o + 4 * e4);
            ax += b2f_(uu.x); ay += b2f_(uu.y); az += b2f_(uu.z); aw += b2f_(uu.w);
        }
        red4[strm][e4] = make_float4(ax, ay, az, aw);
    }
    __syncthreads();
    if (tid < 16) {
        float s[4] = {0.0f, 0.0f, 0.0f, 0.0f};
#pragma unroll
        for (int s16 = 0; s16 < 16; s16++) {
            float4 r = red4[s16][tid];
            s[0] += r.x; s[1] += r.y; s[2] += r.z; s[3] += r.w;
        }
        int e = 4 * tid;
#pragma unroll
        for (int i = 0; i < 4; i++) {
            float v = fmaxf(s[i] + ldin(b_soc, e + i, isbf), 0.0f);
            u[U_ACTH + n * 256 + 64 + e + i] = f2bu(v);
        }
    }
}

// ---- K3: fused gates (MFMA) + LSTM pointwise + output. 256 blocks x 4 agents.
// A rows 4..15 replicate rows 0..3 (only q=0 D-rows used). B coalesced WgF. ----
__global__ __launch_bounds__(256) void gates_out_kernel(
        const void* __restrict__ c0,   const void* __restrict__ b_ih,
        const void* __restrict__ b_hh, const void* __restrict__ b_out,
        const void* __restrict__ Wih_det,
        const float* __restrict__ ws, float* __restrict__ out) {
    __shared__ float gl[4][516];                   // [agent][quad*128 + r], +4 pad
    __shared__ __align__(16) float hnl[4][128];
    const int tid = threadIdx.x;
    const int isbf = detect_bf16(Wih_det, tid);
    const unsigned short* u = (const unsigned short*)ws;
    const short* Ah = (const short*)(u + U_ACTH);
    const short* Wg = (const short*)(u + U_WGF);
    const int lane = tid & 63, wv = tid >> 6, m = lane & 15, q = lane >> 4;
    const int n0 = blockIdx.x * 4;
    // A fragments for agent n0 + (m&3), hoisted (rows 4..15 replicate 0..3)
    short8 ah[8];
#pragma unroll
    for (int kb = 0; kb < 8; kb++)
        ah[kb] = *(const short8*)(Ah + (n0 + (m & 3)) * 256 + kb * 32 + q * 8);
#pragma unroll
    for (int t = 0; t < 8; t++) {
        const int jt = t * 4 + wv;                 // quad = wv, rtile = t
        floatx4 acc = {0.0f, 0.0f, 0.0f, 0.0f};
#pragma unroll
        for (int kb = 0; kb < 8; kb++) {
            short8 b = *(const short8*)(Wg + (jt * 8 + kb) * 512 + q * 128 + m * 8);
            acc = __builtin_amdgcn_mfma_f32_16x16x32_bf16(ah[kb], b, acc, 0, 0, 0);
        }
        if (q == 0) {                              // D rows 0..3 = the 4 agents
            const int jorig = wv * 128 + t * 16 + m;
            const float bias = ldin(b_ih, jorig, isbf) + ldin(b_hh, jorig, isbf);
#pragma unroll
            for (int r = 0; r < 4; r++)
                gl[r][wv * 128 + t * 16 + m] = acc[r] + bias;
        }
    }
    __syncthreads();
    for (int i = tid; i < 512; i += 256) {         // pointwise: 4 agents x 128 r
        int a = i >> 7, r = i & 127;
        int n = n0 + a;
        float iv = gl[a][r],       fv = gl[a][128 + r];
        float gv = gl[a][256 + r], ov = gl[a][384 + r];
        float si = 1.0f / (1.0f + expf(-iv));
        float sf = 1.0f / (1.0f + expf(-fv));
        float so = 1.0f / (1.0f + expf(-ov));
        float cc = sf * ldin(c0, n * 128 + r, isbf) + si * tanhf(gv);
        hnl[a][r] = so * tanhf(cc);
    }
    __syncthreads();
    for (int i = tid; i < 512; i += 256) {         // out proj: 4 agents x 128 j
        int a = i >> 7, j = i & 127;
        if (j < 120) {
            float acc = ldin(b_out, j, isbf);
            for (int r = 0; r < 128; r += 4) {
                float4 hq = *(const float4*)&hnl[a][r];
                acc = fmaf(hq.x, ws[F_WOUT + (r + 0) * 128 + j], acc);
                acc = fmaf(hq.y, ws[F_WOUT + (r + 1) * 128 + j], acc);
                acc = fmaf(hq.z, ws[F_WOUT + (r + 2) * 128 + j], acc);
                acc = fmaf(hq.w, ws[F_WOUT + (r + 3) * 128 + j], acc);
            }
            int ch = j / 20, wc = j - ch * 20;
            out[ch * 20480 + (n0 + a) * 20 + wc] = acc;   // f32, [6][1024][20]
        }
    }
}

extern "C" void kernel_launch(void* const* d_in, const int* in_sizes, int n_in,
                              void* d_out, int out_size, void* d_ws, size_t ws_size,
                              hipStream_t stream) {
    const void* xoff  = d_in[0];
    const void* xabs  = d_in[1];
    const void* h0    = d_in[2];
    const void* c0    = d_in[3];
    const void* W_emb = d_in[4];
    const void* b_emb = d_in[5];
    const void* W_soc = d_in[6];
    const void* b_soc = d_in[7];
    const void* W_ih  = d_in[8];
    const void* W_hh  = d_in[9];
    const void* b_ih  = d_in[10];
    const void* b_hh  = d_in[11];
    const void* W_out = d_in[12];
    const void* b_out = d_in[13];
    float* ws = (float*)d_ws;
    float* out = (float*)d_out;

    prep_kernel<<<424, 256, 0, stream>>>(xoff, h0, W_soc, W_emb, b_emb,
                                         W_ih, W_hh, W_out, ws);
    pgemm_kernel<<<dim3(64, 32), 256, 0, stream>>>(ws);
    pool_kernel<<<1024, 256, 0, stream>>>(xabs, b_soc, W_ih, ws);
    gates_out_kernel<<<256, 256, 0, stream>>>(c0, b_ih, b_hh, b_out, W_ih, ws, out);
}

// Round 20
// 117.426 us; speedup vs baseline: 1.0665x; 1.0665x over previous
//
#include <hip/hip_runtime.h>
#include <hip/hip_bf16.h>

#define NN_ 1024

// ws offsets. ushort: U_*; float: F_*  (~10.3 MB of the 256 MiB ws)
#define U_WGF  0         // 131072: Wg fragment-major REMAPPED:
                         //   ((jt*8+kb)*4+q)*128 + jl*8 + r ; source col
                         //   jorig = (jt&3)*128 + (jt>>2)*16 + jl (quadrant-interleaved)
#define U_SHI  131072    // 524288: W_soc bf16 hi, fragment-major ((g*4+j)*4+q)*512 + e*8 + r
#define U_ACTH 655360    // 262144: act_hi[n][k] 1024x256 (0-63 emb, 64-127 pool, 128-255 h0)
#define U_P    917504    // 4194304: P[m][g*64+e] bf16
#define F_WOUT 2555904   // 16384 f32: WoutT[r][j] 128x128, j>=120 zero
#define F_HN   2572288   // 131072 f32: hn[n][r]

typedef __attribute__((ext_vector_type(8))) short short8;
typedef __attribute__((ext_vector_type(4))) float floatx4;

__device__ __forceinline__ float b2f_(unsigned short u) {
    return __uint_as_float(((unsigned)u) << 16);           // bf16 -> f32, exact
}
__device__ __forceinline__ unsigned short f2bu(float f) {  // f32 -> bf16 bits (RNE)
    __hip_bfloat16 b = __float2bfloat16(f);
    return *(unsigned short*)&b;
}
__device__ __forceinline__ float ldin(const void* p, int i, int isbf) {
    return isbf ? b2f_(((const unsigned short*)p)[i]) : ((const float*)p)[i];
}
__device__ __forceinline__ int detect_bf16(const void* Wih, int tid) {
    unsigned wv = ((const unsigned*)Wih)[tid];
    unsigned e8 = (wv >> 7) & 0xFFu;
    return (__syncthreads_count((e8 >= 96u && e8 <= 134u) ? 1 : 0) > 128) ? 1 : 0;
}

// ---- K0: one-time conversions, 8 elements/thread (424 blocks) ----
__global__ __launch_bounds__(256) void prep_kernel(
        const void* __restrict__ xoff, const void* __restrict__ h0,
        const void* __restrict__ Wsoc, const void* __restrict__ Wemb,
        const void* __restrict__ bemb, const void* __restrict__ Wih,
        const void* __restrict__ Whh,  const void* __restrict__ Wout,
        float* __restrict__ ws) {
    const int tid = threadIdx.x;
    const int isbf = detect_bf16(Wih, tid);
    unsigned short* u = (unsigned short*)ws;
    const int t0 = (blockIdx.x * 256 + tid) * 8;   // regions all 8-aligned
    unsigned short hv[8];
    if (t0 < 131072) {                             // Wg fragment-major, quadrant-remapped
        int jl = (t0 >> 3) & 15, q = (t0 >> 7) & 3, kb = (t0 >> 9) & 7, jt = t0 >> 12;
        int j = (jt & 3) * 128 + (jt >> 2) * 16 + jl;   // quadrant-interleaved source
        int k0 = kb * 32 + q * 8;
#pragma unroll
        for (int r = 0; r < 8; r++) {
            int k = k0 + r;
            float v = (k < 128) ? ldin(Wih, j * 128 + k, isbf)
                                : ldin(Whh, j * 128 + (k - 128), isbf);
            hv[r] = f2bu(v);
        }
        *(short8*)(u + U_WGF + t0) = *(short8*)hv;
    } else if (t0 < 147456) {                      // WoutT f32 [r][j]
        int t2 = t0 - 131072; int r = t2 >> 7, j0 = t2 & 127;
#pragma unroll
        for (int i = 0; i < 8; i++) {
            int j = j0 + i;
            ws[F_WOUT + t2 + i] = (j < 120) ? ldin(Wout, j * 128 + r, isbf) : 0.0f;
        }
    } else if (t0 < 671744) {                      // W_soc hi, fragment-major
        int t2 = t0 - 147456;
        int e = (t2 >> 3) & 63, q = (t2 >> 9) & 3, j = (t2 >> 11) & 3, g = t2 >> 13;
        int src = e * 8192 + g * 128 + j * 32 + q * 8;
#pragma unroll
        for (int r = 0; r < 8; r++) hv[r] = f2bu(ldin(Wsoc, src + r, isbf));
        *(short8*)(u + U_SHI + t2) = *(short8*)hv;
    } else if (t0 < 802816) {                      // h0 -> act k=128..255
        int t2 = t0 - 671744; int n = t2 >> 7, k = t2 & 127;
#pragma unroll
        for (int i = 0; i < 8; i++) hv[i] = f2bu(ldin(h0, t2 + i, isbf));
        *(short8*)(u + U_ACTH + n * 256 + 128 + k) = *(short8*)hv;
    } else {                                       // emb -> act k=0..63
        int t2 = t0 - 802816; int n = t2 >> 6, e0 = t2 & 63;
        float x0 = ldin(xoff, 2 * n, isbf), x1 = ldin(xoff, 2 * n + 1, isbf);
#pragma unroll
        for (int i = 0; i < 8; i++) {
            int e = e0 + i;
            float v = fmaf(x0, ldin(Wemb, 2 * e, isbf),
                      fmaf(x1, ldin(Wemb, 2 * e + 1, isbf), ldin(bemb, e, isbf)));
            hv[i] = f2bu(fmaxf(v, 0.0f));
        }
        *(short8*)(u + U_ACTH + n * 256 + e0) = *(short8*)hv;
    }
}

// ---- K1: P = h0 @ W_socT, hi-only MFMA (8/wave). 2048 blocks, coalesced B ----
__global__ __launch_bounds__(256) void pgemm_kernel(float* __restrict__ ws) {
    const unsigned short* u = (const unsigned short*)ws;
    const short* Ah  = (const short*)(u + U_ACTH);
    const short* Shi = (const short*)(u + U_SHI);
    unsigned short* P16 = (unsigned short*)ws + U_P;
    const int tid = threadIdx.x, lane = tid & 63, wv = tid >> 6;
    const int B_ = blockIdx.y * 64 + blockIdx.x;   // 0..2047
    const int mtile = B_ & 63, rest = B_ >> 6;
    const int cg = rest >> 1, thalf = rest & 1;
    const int m = lane & 15, q = lane >> 4;
    const int g = cg * 4 + wv;                     // wave-uniform B row-group
    const int abase = (mtile * 16 + m) * 256 + 128 + q * 8;
    short8 ah[4];
#pragma unroll
    for (int j = 0; j < 4; j++) ah[j] = *(const short8*)(Ah + abase + 32 * j);
    const int rowl = mtile * 16 + q * 4;
#pragma unroll
    for (int tt = 0; tt < 2; tt++) {
        const int t = thalf * 2 + tt;
        const int e = t * 16 + m;
        floatx4 c = {0.0f, 0.0f, 0.0f, 0.0f};
#pragma unroll
        for (int j = 0; j < 4; j++) {
            short8 bh = *(const short8*)(Shi + ((g * 4 + j) * 4 + q) * 512 + e * 8);
            c = __builtin_amdgcn_mfma_f32_16x16x32_bf16(ah[j], bh, c, 0, 0, 0);
        }
        const int n0 = cg * 256 + wv * 64 + t * 16;
#pragma unroll
        for (int r = 0; r < 4; r++)                // D: col=lane&15, row=q*4+r
            P16[(rowl + r) * 4096 + n0 + m] = f2bu(c[r]);
    }
}

// ---- K2: pool gather, 1 agent/block (1024 blocks); writes act k=64..127 ----
__global__ __launch_bounds__(256) void pool_kernel(const void* __restrict__ xabs,
                                                   const void* __restrict__ b_soc,
                                                   const void* __restrict__ Wih_det,
                                                   float* __restrict__ ws) {
    __shared__ float xabs_s[2048];
    __shared__ int   off[NN_];
    __shared__ int   cnt_s;
    __shared__ float4 red4[16][16];
    const int tid = threadIdx.x;
    const int isbf = detect_bf16(Wih_det, tid);
    const int n = blockIdx.x;
    unsigned short* u = (unsigned short*)ws;

    for (int i = tid; i < 2048; i += 256) xabs_s[i] = ldin(xabs, i, isbf);
    if (tid == 0) cnt_s = 0;
    __syncthreads();
    {
        float xs = xabs_s[2 * n]     - 0.2f;       // x[n] - NS/2
        float ys = xabs_s[2 * n + 1] - 0.2f;
        for (int i = tid; i < NN_; i += 256) {
            float dx = xabs_s[2 * i]     - xs;
            float dy = xabs_s[2 * i + 1] - ys;
            int cx = (int)floorf(dx / 0.4f * 8.0f);
            int cy = (int)floorf(dy / 0.4f * 8.0f);
            bool valid = (dx >= 0.0f) && (dx < 0.4f) && (dy >= 0.0f) && (dy < 0.4f)
                      && (cx >= 0) && (cx < 8) && (cy >= 0) && (cy < 8) && (i != n);
            if (valid) {
                int idx = atomicAdd(&cnt_s, 1);
                off[idx] = i * 4096 + ((cy * 8 + cx) << 6);
            }
        }
    }
    __syncthreads();
    {   // branch-free gathers: 16 streams x 16 e4-lanes
        const unsigned short* P16 = (const unsigned short*)ws + U_P;
        const int strm = tid >> 4, e4 = tid & 15;
        const int cc = cnt_s;
        float ax = 0.0f, ay = 0.0f, az = 0.0f, aw = 0.0f;
        for (int j = strm; j < cc; j += 16) {
            int o = off[j];
            ushort4 uu = *(const ushort4*)(P16 + o + 4 * e4);
            ax += b2f_(uu.x); ay += b2f_(uu.y); az += b2f_(uu.z); aw += b2f_(uu.w);
        }
        red4[strm][e4] = make_float4(ax, ay, az, aw);
    }
    __syncthreads();
    if (tid < 16) {
        float s[4] = {0.0f, 0.0f, 0.0f, 0.0f};
#pragma unroll
        for (int s16 = 0; s16 < 16; s16++) {
            float4 r = red4[s16][tid];
            s[0] += r.x; s[1] += r.y; s[2] += r.z; s[3] += r.w;
        }
        int e = 4 * tid;
#pragma unroll
        for (int i = 0; i < 4; i++) {
            float v = fmaxf(s[i] + ldin(b_soc, e + i, isbf), 0.0f);
            u[U_ACTH + n * 256 + 64 + e + i] = f2bu(v);
        }
    }
}

// ---- K3: gates (hi-only MFMA, quadrant-remapped Wg) + LSTM pointwise -> hn ----
// grid (64,8): block = 16 agents x r-range [16y,16y+16) with ALL 4 quadrants.
__global__ __launch_bounds__(256) void gates_kernel(const void* __restrict__ c0,
                                                    const void* __restrict__ b_ih,
                                                    const void* __restrict__ b_hh,
                                                    const void* __restrict__ Wih_det,
                                                    float* __restrict__ ws) {
    __shared__ float gl[16][68];                   // [agent][quad*16 + jl]
    const int tid = threadIdx.x;
    const int isbf = detect_bf16(Wih_det, tid);
    const unsigned short* u = (const unsigned short*)ws;
    const short* Ah = (const short*)(u + U_ACTH);
    const short* Wg = (const short*)(u + U_WGF);
    const int lane = tid & 63, wv = tid >> 6, m = lane & 15, q = lane >> 4;
    const int m0 = blockIdx.x * 16, y = blockIdx.y;
    const int jt = y * 4 + wv;                     // fragment-major tile id
    floatx4 acc = {0.0f, 0.0f, 0.0f, 0.0f};
#pragma unroll
    for (int kb = 0; kb < 8; kb++) {
        short8 ah = *(const short8*)(Ah + (m0 + m) * 256 + kb * 32 + q * 8);
        short8 b  = *(const short8*)(Wg + (jt * 8 + kb) * 512 + q * 128 + m * 8);
        acc = __builtin_amdgcn_mfma_f32_16x16x32_bf16(ah, b, acc, 0, 0, 0);
    }
    const int jorig = wv * 128 + y * 16 + m;       // quadrant wv, row y*16+m
    const float bias = ldin(b_ih, jorig, isbf) + ldin(b_hh, jorig, isbf);
#pragma unroll
    for (int r = 0; r < 4; r++)                    // D row = q*4+r = agent local
        gl[q * 4 + r][wv * 16 + m] = acc[r] + bias;
    __syncthreads();
    {
        const int a = tid >> 4, rl = tid & 15;     // 16 agents x 16 r
        const int n = m0 + a, rg = y * 16 + rl;
        float iv = gl[a][rl],      fv = gl[a][16 + rl];
        float gv = gl[a][32 + rl], ov = gl[a][48 + rl];
        float si = 1.0f / (1.0f + expf(-iv));
        float sf = 1.0f / (1.0f + expf(-fv));
        float so = 1.0f / (1.0f + expf(-ov));
        float cc = sf * ldin(c0, n * 128 + rg, isbf) + si * tanhf(gv);
        ws[F_HN + n * 128 + rg] = so * tanhf(cc);
    }
}

// ---- K4: output projection from hn (f32 WoutT). 512 blocks, 2 agents ----
__global__ __launch_bounds__(256) void pwout_kernel(const void* __restrict__ b_out,
                                                    const void* __restrict__ Wih_det,
                                                    const float* __restrict__ ws,
                                                    float* __restrict__ out) {
    __shared__ __align__(16) float hnl[2][128];
    const int tid = threadIdx.x;
    const int isbf = detect_bf16(Wih_det, tid);
    const int n0 = blockIdx.x * 2;
    const int half = tid >> 7, t2 = tid & 127;
    const int n = n0 + half;
    hnl[half][t2] = ws[F_HN + n * 128 + t2];
    __syncthreads();
    if (t2 < 120) {
        int j = t2;
        float acc = ldin(b_out, j, isbf);
        for (int r = 0; r < 128; r += 4) {
            float4 hq = *(const float4*)&hnl[half][r];
            acc = fmaf(hq.x, ws[F_WOUT + (r + 0) * 128 + j], acc);
            acc = fmaf(hq.y, ws[F_WOUT + (r + 1) * 128 + j], acc);
            acc = fmaf(hq.z, ws[F_WOUT + (r + 2) * 128 + j], acc);
            acc = fmaf(hq.w, ws[F_WOUT + (r + 3) * 128 + j], acc);
        }
        int ch = j / 20, wc = j - ch * 20;
        out[ch * 20480 + n * 20 + wc] = acc;       // f32, [6][1024][20]
    }
}

extern "C" void kernel_launch(void* const* d_in, const int* in_sizes, int n_in,
                              void* d_out, int out_size, void* d_ws, size_t ws_size,
                              hipStream_t stream) {
    const void* xoff  = d_in[0];
    const void* xabs  = d_in[1];
    const void* h0    = d_in[2];
    const void* c0    = d_in[3];
    const void* W_emb = d_in[4];
    const void* b_emb = d_in[5];
    const void* W_soc = d_in[6];
    const void* b_soc = d_in[7];
    const void* W_ih  = d_in[8];
    const void* W_hh  = d_in[9];
    const void* b_ih  = d_in[10];
    const void* b_hh  = d_in[11];
    const void* W_out = d_in[12];
    const void* b_out = d_in[13];
    float* ws = (float*)d_ws;
    float* out = (float*)d_out;

    prep_kernel<<<424, 256, 0, stream>>>(xoff, h0, W_soc, W_emb, b_emb,
                                         W_ih, W_hh, W_out, ws);
    pgemm_kernel<<<dim3(64, 32), 256, 0, stream>>>(ws);
    pool_kernel<<<1024, 256, 0, stream>>>(xabs, b_soc, W_ih, ws);
    gates_kernel<<<dim3(64, 8), 256, 0, stream>>>(c0, b_ih, b_hh, W_ih, ws);
    pwout_kernel<<<512, 256, 0, stream>>>(b_out, W_ih, ws, out);
}